// Round 2
// baseline (2888.707 us; speedup 1.0000x reference)
//
#include <hip/hip_runtime.h>
#include <math.h>

typedef _Float16 f16;
typedef _Float16 f16x8 __attribute__((ext_vector_type(8)));
typedef float f32x4 __attribute__((ext_vector_type(4)));

#define MFMA_F16(a, b, c) __builtin_amdgcn_mfma_f32_16x16x32_f16((a), (b), (c), 0, 0, 0)

// async global->LDS, 16B per lane. lds base must be wave-uniform; dest = base + lane*16.
__device__ __forceinline__ void async_g2l(void* lds, const void* g) {
  __builtin_amdgcn_global_load_lds((const __attribute__((address_space(1))) void*)g,
                                   (__attribute__((address_space(3))) void*)lds, 16, 0, 0);
}

// ---------------------------------------------------------------------------
// Generic f16 GEMM: C(M x N) = A(M x K) @ B^T where B is (N,K) row-major f16.
// BM in {64,128}, BN=128, BK=32. 256 threads, 4 waves.
// EPI: 0 = write f32 (Cf, ldc, coloff); 1 = write f16 (Ch, ldc); 2 = f16 * scale;
//      3 = f32 add addend[m*addld + c] then write Cf.
// ---------------------------------------------------------------------------
template<int BM, int EPI>
__global__ __launch_bounds__(256) void gemm_k(
    const f16* __restrict__ A, long lda,
    const f16* __restrict__ B,
    float* __restrict__ Cf, f16* __restrict__ Ch, long ldc, long coloff,
    const float* __restrict__ addend, long addld,
    int K, float scale)
{
  constexpr int BK = 32;
  constexpr int MI = 4;                       // per-wave row fragments (64 rows)
  constexpr int NI = (BM == 128) ? 4 : 2;     // per-wave col fragments
  __shared__ f16 As[BM * BK];
  __shared__ f16 Bs[128 * BK];
  const int tid  = threadIdx.x;
  const int lane = tid & 63;
  const int wave = tid >> 6;
  const long m0 = (long)blockIdx.x * BM;
  const long n0 = (long)blockIdx.y * 128;

  const int srow = tid >> 2;          // 0..63
  const int sk8  = (tid & 3) * 8;     // 0,8,16,24

  const f16* ap0 = A + (m0 + srow) * lda + sk8;
  const f16* ap1 = nullptr;
  if constexpr (BM == 128) ap1 = A + (m0 + 64 + srow) * lda + sk8;
  const f16* bp0 = B + (n0 + srow) * (long)K + sk8;
  const f16* bp1 = B + (n0 + 64 + srow) * (long)K + sk8;

  const int fr = lane & 15;
  const int fg = lane >> 4;
  const int wm = (BM == 128) ? (wave >> 1) * 64 : 0;
  const int wn = (BM == 128) ? (wave & 1) * 64 : wave * 32;

  f32x4 acc[MI][NI] = {};

  for (int k0 = 0; k0 < K; k0 += BK) {
    const long kb = (long)k0 * 2;
    async_g2l((char*)As + wave * 1024, (const char*)ap0 + kb);
    if constexpr (BM == 128)
      async_g2l((char*)As + 4096 + wave * 1024, (const char*)ap1 + kb);
    async_g2l((char*)Bs + wave * 1024, (const char*)bp0 + kb);
    async_g2l((char*)Bs + 4096 + wave * 1024, (const char*)bp1 + kb);
    __syncthreads();

    f16x8 af[MI], bf[NI];
#pragma unroll
    for (int mi = 0; mi < MI; ++mi)
      af[mi] = *(const f16x8*)&As[(wm + mi * 16 + fr) * BK + fg * 8];
#pragma unroll
    for (int ni = 0; ni < NI; ++ni)
      bf[ni] = *(const f16x8*)&Bs[(wn + ni * 16 + fr) * BK + fg * 8];
#pragma unroll
    for (int mi = 0; mi < MI; ++mi)
#pragma unroll
      for (int ni = 0; ni < NI; ++ni)
        acc[mi][ni] = MFMA_F16(af[mi], bf[ni], acc[mi][ni]);
    __syncthreads();
  }

#pragma unroll
  for (int mi = 0; mi < MI; ++mi)
#pragma unroll
    for (int ni = 0; ni < NI; ++ni) {
      const long mb = m0 + wm + mi * 16 + fg * 4;
      const long c  = n0 + wn + ni * 16 + fr;
#pragma unroll
      for (int r = 0; r < 4; ++r) {
        const long m = mb + r;
        const float v = acc[mi][ni][r];
        if constexpr (EPI == 0) {
          Cf[m * ldc + coloff + c] = v;
        } else if constexpr (EPI == 1) {
          Ch[m * ldc + c] = (f16)v;
        } else if constexpr (EPI == 2) {
          Ch[m * ldc + c] = (f16)(v * scale);
        } else {
          Cf[m * ldc + coloff + c] = v + addend[m * addld + c];
        }
      }
    }
}

// ---------------------------------------------------------------------------
// Embedding GEMM: C(8192 x 256) = gather_f32(A)[gidx] @ B^T, A fp32 (20000 x lda),
// B f16 (256 x K). BM=64, BN=128, grid (128, 2). fp32 A staged to LDS, converted
// to f16 at fragment-read time.
// ---------------------------------------------------------------------------
__global__ __launch_bounds__(256) void embed_gemm_k(
    const float* __restrict__ A, const int* __restrict__ gidx, long lda,
    const f16* __restrict__ B, float* __restrict__ Cf, long ldc, int K)
{
  constexpr int BK = 32;
  __shared__ float Asf[64 * BK];
  __shared__ f16 Bs[128 * BK];
  const int tid  = threadIdx.x;
  const int lane = tid & 63;
  const int wave = tid >> 6;
  const long m0 = (long)blockIdx.x * 64;
  const long n0 = (long)blockIdx.y * 128;

  // A staging (fp32): wave w, chunk j covers rows j*32 + w*8 + (lane>>3),
  // cols (lane&7)*4 .. +3  (16B per lane, 8 lanes per 128B row).
  const int arow = lane >> 3;
  const int acol = (lane & 7) * 4;
  const float* apA = A + (long)gidx[m0 + wave * 8 + arow] * lda + acol;
  const float* apB = A + (long)gidx[m0 + 32 + wave * 8 + arow] * lda + acol;

  // B staging (f16): rows srow, cols sk8 (same as gemm_k).
  const int srow = tid >> 2;
  const int sk8  = (tid & 3) * 8;
  const f16* bp0 = B + (n0 + srow) * (long)K + sk8;
  const f16* bp1 = B + (n0 + 64 + srow) * (long)K + sk8;

  const int fr = lane & 15;
  const int fg = lane >> 4;
  const int wn = wave * 32;

  f32x4 acc[4][2] = {};

  for (int k0 = 0; k0 < K; k0 += BK) {
    async_g2l((char*)Asf + wave * 1024, (const char*)apA + (long)k0 * 4);
    async_g2l((char*)Asf + 4096 + wave * 1024, (const char*)apB + (long)k0 * 4);
    async_g2l((char*)Bs + wave * 1024, (const char*)bp0 + (long)k0 * 2);
    async_g2l((char*)Bs + 4096 + wave * 1024, (const char*)bp1 + (long)k0 * 2);
    __syncthreads();

    f16x8 af[4], bf[2];
#pragma unroll
    for (int mi = 0; mi < 4; ++mi) {
      const float* ar = &Asf[(mi * 16 + fr) * BK + fg * 8];
#pragma unroll
      for (int e = 0; e < 8; ++e) af[mi][e] = (f16)ar[e];
    }
#pragma unroll
    for (int ni = 0; ni < 2; ++ni)
      bf[ni] = *(const f16x8*)&Bs[(wn + ni * 16 + fr) * BK + fg * 8];
#pragma unroll
    for (int mi = 0; mi < 4; ++mi)
#pragma unroll
      for (int ni = 0; ni < 2; ++ni)
        acc[mi][ni] = MFMA_F16(af[mi], bf[ni], acc[mi][ni]);
    __syncthreads();
  }

#pragma unroll
  for (int mi = 0; mi < 4; ++mi)
#pragma unroll
    for (int ni = 0; ni < 2; ++ni) {
      const long mb = m0 + mi * 16 + fg * 4;
      const long c  = n0 + wn + ni * 16 + fr;
#pragma unroll
      for (int r = 0; r < 4; ++r)
        Cf[(mb + r) * ldc + c] = acc[mi][ni][r];
    }
}

// ---------------------------------------------------------------------------
// SwiGLU GEMM: reads xn (M x 256) and w1 (2048 x 256); computes for output col
// j in [0,1024): g = silu(xn@w1[1024+j]) * (xn@w1[j]); writes f16 G (M x 1024).
// ---------------------------------------------------------------------------
__global__ __launch_bounds__(256) void gemm_swiglu_k(
    const f16* __restrict__ A, const f16* __restrict__ B,
    f16* __restrict__ G, int K)
{
  constexpr int BK = 32;
  __shared__ f16 As[128 * BK];
  __shared__ f16 B1s[128 * BK];
  __shared__ f16 B2s[128 * BK];
  const int tid  = threadIdx.x;
  const int lane = tid & 63;
  const int wave = tid >> 6;
  const long m0 = (long)blockIdx.x * 128;
  const long n0 = (long)blockIdx.y * 128;

  const int srow = tid >> 2;
  const int sk8  = (tid & 3) * 8;
  const f16* ap0 = A + (m0 + srow) * (long)K + sk8;
  const f16* ap1 = A + (m0 + 64 + srow) * (long)K + sk8;
  const f16* b10 = B + (n0 + srow) * (long)K + sk8;
  const f16* b11 = B + (n0 + 64 + srow) * (long)K + sk8;
  const f16* b20 = B + (1024 + n0 + srow) * (long)K + sk8;
  const f16* b21 = B + (1024 + n0 + 64 + srow) * (long)K + sk8;

  const int fr = lane & 15;
  const int fg = lane >> 4;
  const int wm = (wave >> 1) * 64;
  const int wn = (wave & 1) * 64;

  f32x4 acc1[4][4] = {};
  f32x4 acc2[4][4] = {};

  for (int k0 = 0; k0 < K; k0 += BK) {
    const long kb = (long)k0 * 2;
    async_g2l((char*)As + wave * 1024, (const char*)ap0 + kb);
    async_g2l((char*)As + 4096 + wave * 1024, (const char*)ap1 + kb);
    async_g2l((char*)B1s + wave * 1024, (const char*)b10 + kb);
    async_g2l((char*)B1s + 4096 + wave * 1024, (const char*)b11 + kb);
    async_g2l((char*)B2s + wave * 1024, (const char*)b20 + kb);
    async_g2l((char*)B2s + 4096 + wave * 1024, (const char*)b21 + kb);
    __syncthreads();

    f16x8 af[4], b1f[4], b2f[4];
#pragma unroll
    for (int mi = 0; mi < 4; ++mi)
      af[mi] = *(const f16x8*)&As[(wm + mi * 16 + fr) * BK + fg * 8];
#pragma unroll
    for (int ni = 0; ni < 4; ++ni) {
      b1f[ni] = *(const f16x8*)&B1s[(wn + ni * 16 + fr) * BK + fg * 8];
      b2f[ni] = *(const f16x8*)&B2s[(wn + ni * 16 + fr) * BK + fg * 8];
    }
#pragma unroll
    for (int mi = 0; mi < 4; ++mi)
#pragma unroll
      for (int ni = 0; ni < 4; ++ni) {
        acc1[mi][ni] = MFMA_F16(af[mi], b1f[ni], acc1[mi][ni]);
        acc2[mi][ni] = MFMA_F16(af[mi], b2f[ni], acc2[mi][ni]);
      }
    __syncthreads();
  }

#pragma unroll
  for (int mi = 0; mi < 4; ++mi)
#pragma unroll
    for (int ni = 0; ni < 4; ++ni) {
      const long mb = m0 + wm + mi * 16 + fg * 4;
      const long c  = n0 + wn + ni * 16 + fr;
#pragma unroll
      for (int r = 0; r < 4; ++r) {
        const float h1v = acc1[mi][ni][r];
        const float gt  = acc2[mi][ni][r];
        const float sg  = gt / (1.0f + __expf(-gt));
        G[(mb + r) * 1024 + c] = (f16)(h1v * sg);
      }
    }
}

// ---------------------------------------------------------------------------
// Attention: one block per (b, head). n=128, dim_head=32.
// Q: (M, ldq) f16 (already scaled); KV: (M,128) f16, k=cols 0..31, v=cols 32..63.
// O: (M, ldo) f16. Wave-parallel register softmax.
// ---------------------------------------------------------------------------
__global__ __launch_bounds__(256) void attn_k(
    const f16* __restrict__ Q, int ldq,
    const f16* __restrict__ KV,
    f16* __restrict__ O, int ldo)
{
  const int b = blockIdx.x, h = blockIdx.y;
  __shared__ f16 Qs[128 * 32];
  __shared__ f16 Ks[128 * 32];
  __shared__ f16 Vt[32 * 136];   // transposed V, padded stride
  __shared__ f16 P[128 * 136];   // softmax probs, padded stride
  const int tid  = threadIdx.x;
  const int lane = tid & 63;
  const int wave = tid >> 6;
  const int fr = lane & 15;
  const int fg = lane >> 4;
  const long mrow = (long)b * 128;

  for (int i = tid; i < 512; i += 256) {
    int row = i >> 2, c8 = (i & 3) * 8;
    *(f16x8*)&Qs[row * 32 + c8] = *(const f16x8*)&Q[(mrow + row) * ldq + h * 32 + c8];
    *(f16x8*)&Ks[row * 32 + c8] = *(const f16x8*)&KV[(mrow + row) * 128 + c8];
  }
  for (int i = tid; i < 4096; i += 256) {
    int n = i >> 5, d = i & 31;
    Vt[d * 136 + n] = KV[(mrow + n) * 128 + 32 + d];
  }
  __syncthreads();

  const int wm = wave * 32;
  f32x4 c[2][8];
  {
    f16x8 a0 = *(const f16x8*)&Qs[(wm + fr) * 32 + fg * 8];
    f16x8 a1 = *(const f16x8*)&Qs[(wm + 16 + fr) * 32 + fg * 8];
#pragma unroll
    for (int ni = 0; ni < 8; ++ni) {
      f16x8 bf = *(const f16x8*)&Ks[(ni * 16 + fr) * 32 + fg * 8];
      f32x4 z0 = {};
      f32x4 z1 = {};
      c[0][ni] = MFMA_F16(a0, bf, z0);
      c[1][ni] = MFMA_F16(a1, bf, z1);
    }
  }
  // softmax: row = wm + mi*16 + fg*4 + r lives in the 16 lanes sharing fg.
#pragma unroll
  for (int mi = 0; mi < 2; ++mi) {
#pragma unroll
    for (int r = 0; r < 4; ++r) {
      float mx = c[mi][0][r];
#pragma unroll
      for (int ni = 1; ni < 8; ++ni) mx = fmaxf(mx, c[mi][ni][r]);
#pragma unroll
      for (int o = 1; o < 16; o <<= 1) mx = fmaxf(mx, __shfl_xor(mx, o, 64));
      float e[8];
      float sum = 0.f;
#pragma unroll
      for (int ni = 0; ni < 8; ++ni) { e[ni] = __expf(c[mi][ni][r] - mx); sum += e[ni]; }
#pragma unroll
      for (int o = 1; o < 16; o <<= 1) sum += __shfl_xor(sum, o, 64);
      const float inv = 1.0f / sum;
      const int prow = wm + mi * 16 + fg * 4 + r;
#pragma unroll
      for (int ni = 0; ni < 8; ++ni)
        P[prow * 136 + ni * 16 + fr] = (f16)(e[ni] * inv);
    }
  }
  __syncthreads();

  f32x4 acc[2][2] = {};
#pragma unroll
  for (int k0 = 0; k0 < 128; k0 += 32) {
    f16x8 p0 = *(const f16x8*)&P[(wm + fr) * 136 + k0 + fg * 8];
    f16x8 p1 = *(const f16x8*)&P[(wm + 16 + fr) * 136 + k0 + fg * 8];
    f16x8 v0 = *(const f16x8*)&Vt[fr * 136 + k0 + fg * 8];
    f16x8 v1 = *(const f16x8*)&Vt[(16 + fr) * 136 + k0 + fg * 8];
    acc[0][0] = MFMA_F16(p0, v0, acc[0][0]);
    acc[0][1] = MFMA_F16(p0, v1, acc[0][1]);
    acc[1][0] = MFMA_F16(p1, v0, acc[1][0]);
    acc[1][1] = MFMA_F16(p1, v1, acc[1][1]);
  }
#pragma unroll
  for (int mi = 0; mi < 2; ++mi)
#pragma unroll
    for (int ni = 0; ni < 2; ++ni)
#pragma unroll
      for (int r = 0; r < 4; ++r)
        O[(mrow + wm + mi * 16 + fg * 4 + r) * ldo + h * 32 + ni * 16 + fr] =
            (f16)acc[mi][ni][r];
}

// ---------------------------------------------------------------------------
// LayerNorm (gamma only, eps 1e-5) over 256 cols; one wave per row.
// MODE 0: f32 input. MODE 1: f32 input with fold-in of row L2-normalize.
// MODE 2: gather fp32 table rows via gidx. Output f16.
// ---------------------------------------------------------------------------
template<int MODE>
__global__ __launch_bounds__(256) void ln_k(
    const float* __restrict__ X, const float* __restrict__ T,
    const int* __restrict__ gidx,
    const float* __restrict__ gamma, f16* __restrict__ Out)
{
  const int row  = blockIdx.x * 4 + (threadIdx.x >> 6);
  const int lane = threadIdx.x & 63;
  float v[4];
  if constexpr (MODE == 2) {
    const float* src = T + (long)gidx[row] * 256;
#pragma unroll
    for (int j = 0; j < 4; ++j) v[j] = src[lane + 64 * j];
  } else {
    const float* src = X + (long)row * 256;
#pragma unroll
    for (int j = 0; j < 4; ++j) v[j] = src[lane + 64 * j];
  }
  float s1 = v[0] + v[1] + v[2] + v[3];
  float s2 = v[0] * v[0] + v[1] * v[1] + v[2] * v[2] + v[3] * v[3];
#pragma unroll
  for (int o = 32; o > 0; o >>= 1) {
    s1 += __shfl_xor(s1, o, 64);
    s2 += __shfl_xor(s2, o, 64);
  }
  float c = 1.0f;
  if constexpr (MODE == 1) c = 1.0f / fmaxf(sqrtf(s2), 1e-12f);
  const float mu  = c * s1 * (1.0f / 256.0f);
  const float ex2 = c * c * s2 * (1.0f / 256.0f);
  const float rs  = rsqrtf(ex2 - mu * mu + 1e-5f);
#pragma unroll
  for (int j = 0; j < 4; ++j) {
    const int col = lane + 64 * j;
    Out[(long)row * 256 + col] = (f16)(gamma[col] * (c * v[j] - mu) * rs);
  }
}

// f32 -> f16 weight conversion with optional row padding (pad rows = 0).
__global__ void convert_pad(const float* __restrict__ src, f16* __restrict__ dst,
                            int nm, int rs, int rp, int cols, long total)
{
  const long i = (long)blockIdx.x * 256 + threadIdx.x;
  if (i >= total) return;
  const long c = i % cols;
  const long r = (i / cols) % rp;
  const long m = i / ((long)cols * rp);
  dst[i] = (r < rs) ? (f16)src[(m * rs + r) * cols + c] : (f16)0.f;
}

// split z -> query/positive/negative views.
__global__ void extract_k(const float* __restrict__ z, float* __restrict__ q,
                          float* __restrict__ p, float* __restrict__ neg)
{
  const long i = (long)blockIdx.x * 256 + threadIdx.x;
  if (i >= 64L * 128 * 1536) return;
  const int c = (int)(i % 1536);
  const int n = (int)((i / 1536) % 128);
  const int b = (int)(i / (1536L * 128));
  const float v = z[i];
  if (n == 0) {
    q[(long)b * 1536 + c] = v;
  } else {
    if (n == 1) p[(long)b * 1536 + c] = v;
    neg[((long)b * 127 + (n - 1)) * 1536 + c] = v;
  }
}

// ---------------------------------------------------------------------------
// Host-side: one transformer block.
// ---------------------------------------------------------------------------
static void run_block(hipStream_t stream,
    const float* x, const float* gx,
    const float* y, const float* gy,
    bool normx, const f16* ynpre,
    const f16* wq, int nq,
    const f16* wkv, const f16* wout, int kout,
    const f16* w1, const f16* w2, int heads,
    float* dest, long ldc, long coloff,
    f16* xn, f16* yn, f16* qb, f16* kvb, f16* attnb, float* tmp, f16* gb)
{
  const float scale = 0.17677669529663687f;  // 32^-0.5
  if (normx) ln_k<1><<<2048, 256, 0, stream>>>(x, nullptr, nullptr, gx, xn);
  else       ln_k<0><<<2048, 256, 0, stream>>>(x, nullptr, nullptr, gx, xn);
  const f16* ynp = xn;
  if (ynpre) {
    ynp = ynpre;
  } else if (y) {
    ln_k<0><<<2048, 256, 0, stream>>>(y, nullptr, nullptr, gy, yn);
    ynp = yn;
  }
  // q = xn @ wq^T * scale  (f16 out)
  gemm_k<64, 2><<<dim3(128, nq / 128), 256, 0, stream>>>(
      xn, 256, wq, nullptr, qb, nq, 0, nullptr, 0, 256, scale);
  // kv = yn @ wkv^T (f16 out, padded N=128)
  if (wkv)
    gemm_k<64, 1><<<dim3(128, 1), 256, 0, stream>>>(
        ynp, 256, wkv, nullptr, kvb, 128, 0, nullptr, 0, 256, 0.f);
  attn_k<<<dim3(64, heads), 256, 0, stream>>>(qb, nq, kvb, attnb, kout);
  // tmp = attn @ wout^T (f32)
  gemm_k<64, 0><<<dim3(128, 2), 256, 0, stream>>>(
      attnb, kout, wout, tmp, nullptr, 256, 0, nullptr, 0, kout, 0.f);
  // g = swiglu(xn @ w1^T) (f16)
  gemm_swiglu_k<<<dim3(64, 8), 256, 0, stream>>>(xn, w1, gb, 256);
  // dest = g @ w2^T + tmp (f32)
  gemm_k<64, 3><<<dim3(128, 2), 256, 0, stream>>>(
      gb, 1024, w2, dest, nullptr, ldc, coloff, tmp, 256, 1024, 0.f);
}

extern "C" void kernel_launch(void* const* d_in, const int* in_sizes, int n_in,
                              void* d_out, int out_size, void* d_ws, size_t ws_size,
                              hipStream_t stream)
{
  const int*   batch      = (const int*)d_in[0];
  const float* llm_tables = (const float*)d_in[1];   // harness stages f16 as f32
  const float* poi        = (const float*)d_in[2];   // harness stages f16 as f32
  const float* w_hidden   = (const float*)d_in[3];
  const float* sa_gamma   = (const float*)d_in[4];
  const float* sa_wq      = (const float*)d_in[5];
  const float* sa_wkv     = (const float*)d_in[6];
  const float* sa_wout    = (const float*)d_in[7];
  const float* sa_w1      = (const float*)d_in[8];
  const float* sa_w2      = (const float*)d_in[9];
  const float* ca_gx      = (const float*)d_in[10];
  const float* ca_gy      = (const float*)d_in[11];
  const float* ca_wq      = (const float*)d_in[12];
  const float* ca_wkv     = (const float*)d_in[13];
  const float* ca_wout    = (const float*)d_in[14];
  const float* ca_w1      = (const float*)d_in[15];
  const float* ca_w2      = (const float*)d_in[16];
  const float* fa_gx      = (const float*)d_in[17];
  const float* fa_gy      = (const float*)d_in[18];
  const float* fa_wq      = (const float*)d_in[19];
  const float* fa_wkv     = (const float*)d_in[20];
  const float* fa_wout    = (const float*)d_in[21];
  const float* fa_w1      = (const float*)d_in[22];
  const float* fa_w2      = (const float*)d_in[23];
  (void)in_sizes; (void)n_in; (void)out_size; (void)ws_size;

  char* w = (char*)d_ws;
  auto take = [&](size_t n) { void* p = (void*)w; w += (n + 255) & ~(size_t)255; return p; };
  f16* sawq16  = (f16*)take(2ull * 256 * 256 * 2);
  f16* sawkv16 = (f16*)take(2ull * 128 * 256 * 2);
  f16* sawo16  = (f16*)take(2ull * 256 * 256 * 2);
  f16* saw116  = (f16*)take(2ull * 2048 * 256 * 2);
  f16* saw216  = (f16*)take(2ull * 256 * 1024 * 2);
  f16* cawq16  = (f16*)take(6ull * 256 * 256 * 2);
  f16* cawkv16 = (f16*)take(6ull * 128 * 256 * 2);
  f16* cawo16  = (f16*)take(6ull * 256 * 256 * 2);
  f16* caw116  = (f16*)take(6ull * 2048 * 256 * 2);
  f16* caw216  = (f16*)take(6ull * 256 * 1024 * 2);
  f16* fawq16  = (f16*)take(128ull * 256 * 2);
  f16* fawkv16 = (f16*)take(128ull * 256 * 2);
  f16* fawo16  = (f16*)take(256ull * 32 * 2);
  f16* faw116  = (f16*)take(2048ull * 256 * 2);
  f16* faw216  = (f16*)take(256ull * 1024 * 2);
  f16* wh16    = (f16*)take(2ull * 256 * 4096 * 2);
  float* hbuf  = (float*)take(8192ull * 256 * 4);
  float* x1    = (float*)take(8192ull * 256 * 4);
  float* x2    = (float*)take(8192ull * 256 * 4);
  float* xc    = (float*)take(8192ull * 256 * 4);
  f16* xn      = (f16*)take(8192ull * 256 * 2);
  f16* yn      = (f16*)take(8192ull * 256 * 2);
  f16* ynf     = (f16*)take(8192ull * 256 * 2);
  f16* qb      = (f16*)take(8192ull * 256 * 2);
  f16* kvb     = (f16*)take(8192ull * 128 * 2);
  f16* kvf     = (f16*)take(8192ull * 128 * 2);
  f16* attnb   = (f16*)take(8192ull * 256 * 2);
  float* tmp   = (float*)take(8192ull * 256 * 4);
  f16* gb      = (f16*)take(8192ull * 1024 * 2);

  auto conv = [&](const float* src, f16* dst, int nm, int rs, int rp, int cols) {
    long total = (long)nm * rp * cols;
    convert_pad<<<(int)((total + 255) / 256), 256, 0, stream>>>(src, dst, nm, rs, rp, cols, total);
  };
  conv(w_hidden, wh16, 2, 256, 256, 4096);
  conv(sa_wq,   sawq16,  2, 256,  256,  256);
  conv(sa_wkv,  sawkv16, 2, 64,   128,  256);
  conv(sa_wout, sawo16,  2, 256,  256,  256);
  conv(sa_w1,   saw116,  2, 2048, 2048, 256);
  conv(sa_w2,   saw216,  2, 256,  256,  1024);
  conv(ca_wq,   cawq16,  6, 256,  256,  256);
  conv(ca_wkv,  cawkv16, 6, 64,   128,  256);
  conv(ca_wout, cawo16,  6, 256,  256,  256);
  conv(ca_w1,   caw116,  6, 2048, 2048, 256);
  conv(ca_w2,   caw216,  6, 256,  256,  1024);
  conv(fa_wq,   fawq16,  1, 32,   128,  256);
  conv(fa_wkv,  fawkv16, 1, 64,   128,  256);
  conv(fa_wout, fawo16,  1, 256,  256,  32);
  conv(fa_w1,   faw116,  1, 2048, 2048, 256);
  conv(fa_w2,   faw216,  1, 256,  256,  1024);

  // Fused-block yn (shared across all 6): LN(gather(poi), fa_gy), then kv once.
  ln_k<2><<<2048, 256, 0, stream>>>(nullptr, poi, batch, fa_gy, ynf);
  gemm_k<64, 1><<<dim3(128, 1), 256, 0, stream>>>(
      ynf, 256, fawkv16, nullptr, kvf, 128, 0, nullptr, 0, 256, 0.f);

  // Embed + self blocks for tables 0,1 (table 2's self output is unused).
  float* xout[2] = {x1, x2};
  for (int t = 0; t < 2; ++t) {
    embed_gemm_k<<<dim3(128, 2), 256, 0, stream>>>(
        llm_tables + (long)t * 20000 * 4096, batch, 4096,
        wh16 + (long)t * 256 * 4096, hbuf, 256, 4096);
    run_block(stream, hbuf, sa_gamma + t * 256, nullptr, nullptr, true, nullptr,
              sawq16 + t * 65536, 256, sawkv16 + t * 32768, sawo16 + t * 65536, 256,
              saw116 + (long)t * 524288, saw216 + (long)t * 262144, 8,
              xout[t], 256, 0, xn, yn, qb, kvb, attnb, tmp, gb);
  }
  // Cross block i -> xc; fused block i -> z columns [i*256, i*256+256).
  for (int i = 0; i < 6; ++i) {
    run_block(stream, x1, ca_gx + i * 256, x2, ca_gy + i * 256, false, nullptr,
              cawq16 + i * 65536, 256, cawkv16 + i * 32768, cawo16 + i * 65536, 256,
              caw116 + (long)i * 524288, caw216 + (long)i * 262144, 8,
              xc, 256, 0, xn, yn, qb, kvb, attnb, tmp, gb);
    run_block(stream, xc, fa_gx, nullptr, nullptr, false, ynf,
              fawq16, 128, nullptr, fawo16, 32,
              faw116, faw216, 1,
              (float*)d_out, 1536, (long)i * 256, xn, yn, qb, kvf, attnb, tmp, gb);
  }

  {
    float* z = (float*)d_out;
    long total = 64L * 128 * 1536;
    extract_k<<<(int)((total + 255) / 256), 256, 0, stream>>>(
        z, z + 12582912, z + 12681216, z + 12779520);
  }
}